// Round 8
// baseline (477.626 us; speedup 1.0000x reference)
//
#include <hip/hip_runtime.h>

#define DEVINL __device__ __forceinline__

// lower-tri packed index, requires i >= j
#define TIX(i, j) ((i) * ((i) + 1) / 2 + (j))
// symmetric access (compile-time resolved under full unroll)
#define SYM(arr, i, j) ((i) >= (j) ? arr[TIX(i, j)] : arr[TIX(j, i)])

DEVINL void inv4(const float* m, float* inv) {
    float s0 = m[0] * m[5] - m[1] * m[4];
    float s1 = m[0] * m[6] - m[2] * m[4];
    float s2 = m[0] * m[7] - m[3] * m[4];
    float s3 = m[1] * m[6] - m[2] * m[5];
    float s4 = m[1] * m[7] - m[3] * m[5];
    float s5 = m[2] * m[7] - m[3] * m[6];
    float c5 = m[10] * m[15] - m[11] * m[14];
    float c4 = m[9] * m[15] - m[11] * m[13];
    float c3 = m[9] * m[14] - m[10] * m[13];
    float c2 = m[8] * m[15] - m[11] * m[12];
    float c1 = m[8] * m[14] - m[10] * m[12];
    float c0 = m[8] * m[13] - m[9] * m[12];
    float det = s0 * c5 - s1 * c4 + s2 * c3 + s3 * c2 - s4 * c1 + s5 * c0;
    float id = 1.0f / det;
    inv[0]  = ( m[5] * c5 - m[6] * c4 + m[7] * c3) * id;
    inv[1]  = (-m[1] * c5 + m[2] * c4 - m[3] * c3) * id;
    inv[2]  = ( m[13] * s5 - m[14] * s4 + m[15] * s3) * id;
    inv[3]  = (-m[9] * s5 + m[10] * s4 - m[11] * s3) * id;
    inv[4]  = (-m[4] * c5 + m[6] * c2 - m[7] * c1) * id;
    inv[5]  = ( m[0] * c5 - m[2] * c2 + m[3] * c1) * id;
    inv[6]  = (-m[12] * s5 + m[14] * s2 - m[15] * s1) * id;
    inv[7]  = ( m[8] * s5 - m[10] * s2 + m[11] * s1) * id;
    inv[8]  = ( m[4] * c4 - m[5] * c2 + m[7] * c0) * id;
    inv[9]  = (-m[0] * c4 + m[1] * c2 - m[3] * c0) * id;
    inv[10] = ( m[12] * s4 - m[13] * s2 + m[15] * s0) * id;
    inv[11] = (-m[8] * s4 + m[9] * s2 - m[11] * s0) * id;
    inv[12] = (-m[4] * c3 + m[5] * c1 - m[6] * c0) * id;
    inv[13] = ( m[0] * c3 - m[1] * c1 + m[2] * c0) * id;
    inv[14] = (-m[12] * s3 + m[13] * s1 - m[14] * s0) * id;
    inv[15] = ( m[8] * s3 - m[9] * s1 + m[10] * s0) * id;
}

// TWO LANES PER BATCH: lane pair (l, l+32) shares batch q = l&31; half
// p = l>>5 owns rows/cols 4p..4p+3 of each 8-dim object. Per-lane register
// peak ~104 nominal -> __launch_bounds__(64,4) pins VGPR<=128 => 4 waves/SIMD
// (16 blocks/CU; LDS 9216B x16 = 147KB fits). Rationale: R1-R7 all landed in
// the 129-256 VGPR bin (2 waves/SIMD) and pinned at ~6-7us/body/CU with
// VALUBusy ~13%; R2 (VGPR 84) proved occupancy jumps to ~26% in the <=128 bin.
// Cross-lane: ~116 shfl_xor(.,32)/lane (F rows, ns, S-merge, HP rows).
// Shared objects (P, H, Lq, Lr) read broadcast-style by both lanes from LDS.
__global__ __launch_bounds__(64, 4) void ekf_kernel(
    const float* __restrict__ meas,   // (B,4)
    const float* __restrict__ state,  // (B,8)
    const float* __restrict__ Pin,    // (B,8,8) symmetric
    const float* __restrict__ Fin,    // (B,8,8)
    const float* __restrict__ Hin,    // (B,4,8)
    const float* __restrict__ pnin,   // (B,36)
    const float* __restrict__ mnin,   // (B,10)
    float* __restrict__ out_pred,     // (B,4)
    float* __restrict__ out_state,    // (B,8)
    float* __restrict__ out_cov)      // (B,8,8)
{
    const int t  = threadIdx.x;
    const int q  = t & 31;            // batch within block
    const int p  = t >> 5;            // owned half (rows/cols 4p..4p+3)
    const bool hi = (p != 0);
    const int bb = blockIdx.x * 32;
    const int b  = bb + q;

    __shared__ float4 arena[576];     // 9216 B; 16 blocks/CU fits 147KB

    // ======== stage state (pad-3), prefetch meas ========
    {
        const float4* g = reinterpret_cast<const float4*>(state) + (size_t)bb * 2;
        arena[(t >> 1) * 3 + (t & 1)] = g[t];   // 64 f4 exactly
    }
    float4 z = *(reinterpret_cast<const float4*>(meas) + b);  // used late
    __syncthreads();
    float s_[8];
    {
        float4 a = arena[q * 3 + 0], c = arena[q * 3 + 1];
        s_[0] = a.x; s_[1] = a.y; s_[2] = a.z; s_[3] = a.w;
        s_[4] = c.x; s_[5] = c.y; s_[6] = c.z; s_[7] = c.w;
    }

    // ======== stage P (stride 17) -> Ps[36] (both lanes full, broadcast) ========
    {
        const float4* g = reinterpret_cast<const float4*>(Pin) + (size_t)bb * 16;
        #pragma unroll
        for (int i = 0; i < 8; ++i) {
            int f = i * 64 + t;
            arena[(f >> 4) * 17 + (f & 15)] = g[f];
        }
    }
    __syncthreads();
    float Ps[36];
    #pragma unroll
    for (int sI = 0; sI < 16; ++sI) {
        float4 v = arena[q * 17 + sI];
        const int row = sI >> 1, c0 = (sI & 1) * 4;
        if (c0 + 0 <= row) Ps[TIX(row, c0 + 0)] = v.x;
        if (c0 + 1 <= row) Ps[TIX(row, c0 + 1)] = v.y;
        if (c0 + 2 <= row) Ps[TIX(row, c0 + 2)] = v.z;
        if (c0 + 3 <= row) Ps[TIX(row, c0 + 3)] = v.w;
    }

    // ======== stage F (stride 17) -> own 4 rows Fh[r*8+k] ========
    {
        const float4* g = reinterpret_cast<const float4*>(Fin) + (size_t)bb * 16;
        #pragma unroll
        for (int i = 0; i < 8; ++i) {
            int f = i * 64 + t;
            arena[(f >> 4) * 17 + (f & 15)] = g[f];
        }
    }
    __syncthreads();
    float Fh[32];   // rows 4p..4p+3
    #pragma unroll
    for (int j = 0; j < 8; ++j) {   // slot s = 8p+j : row 4p+(j>>1), colhalf j&1
        float4 v = arena[q * 17 + 8 * p + j];
        const int r = j >> 1, c0 = 4 * (j & 1);
        Fh[r * 8 + c0 + 0] = v.x; Fh[r * 8 + c0 + 1] = v.y;
        Fh[r * 8 + c0 + 2] = v.z; Fh[r * 8 + c0 + 3] = v.w;
    }

    // ======== predict (a): ns_own, G = P F^T columns 4p..4p+3 ========
    float ns_own[4];
    #pragma unroll
    for (int r = 0; r < 4; ++r) {
        float acc = 0.f;
        #pragma unroll
        for (int k = 0; k < 8; ++k) acc += Fh[r * 8 + k] * s_[k];
        ns_own[r] = acc;
    }
    float Gc[32];  // Gc[j*4+lr] = sum_k P[j,k] F[4p+lr,k]
    #pragma unroll
    for (int j = 0; j < 8; ++j)
        #pragma unroll
        for (int lr = 0; lr < 4; ++lr) {
            float acc = 0.f;
            #pragma unroll
            for (int k = 0; k < 8; ++k) acc += SYM(Ps, j, k) * Fh[lr * 8 + k];
            Gc[j * 4 + lr] = acc;
        }
    // Ps, s_ dead

    // ======== predict (b): Pnc[i][lr] = sum_j F[i,j] Gc[j][lr] ========
    float Pnc[32];  // [i*4+lr], i = global row, lr local col
    #pragma unroll
    for (int i = 0; i < 8; ++i) {
        const int r = i & 3;
        const bool own = ((i >> 2) == p);
        float fr[8];
        #pragma unroll
        for (int k = 0; k < 8; ++k) {
            float sh = __shfl_xor(Fh[r * 8 + k], 32);
            fr[k] = own ? Fh[r * 8 + k] : sh;
        }
        #pragma unroll
        for (int lr = 0; lr < 4; ++lr) {
            float acc = 0.f;
            #pragma unroll
            for (int j = 0; j < 8; ++j) acc += fr[j] * Gc[j * 4 + lr];
            Pnc[i * 4 + lr] = acc;
        }
    }
    // Fh, Gc dead

    // ======== stage pn [0,288) + H [288,576) ========
    {
        const float4* g = reinterpret_cast<const float4*>(pnin) + (size_t)bb * 9;
        #pragma unroll
        for (int i = 0; i < 5; ++i) {
            int f = i * 64 + t;
            if (f < 288) arena[f] = g[f];
        }
        const float4* gh = reinterpret_cast<const float4*>(Hin) + (size_t)bb * 8;
        #pragma unroll
        for (int i = 0; i < 4; ++i) {
            int f = i * 64 + t;
            arena[288 + (f >> 3) * 9 + (f & 7)] = gh[f];
        }
    }
    __syncthreads();

    // ======== Q = Lq Lq^T accumulated into own columns ========
    {
        float Lq[36];
        #pragma unroll
        for (int rr = 0; rr < 9; ++rr) {
            float4 v = arena[q * 9 + rr];
            Lq[4 * rr + 0] = v.x; Lq[4 * rr + 1] = v.y;
            Lq[4 * rr + 2] = v.z; Lq[4 * rr + 3] = v.w;
        }
        float Ld[32];  // dense own L rows (l = 4p+lr), zeros beyond diag
        #pragma unroll
        for (int lr = 0; lr < 4; ++lr)
            #pragma unroll
            for (int k = 0; k < 8; ++k) {
                float lo  = (k <= lr)     ? Lq[TIX(lr, k)]     : 0.f;
                float hif = (k <= 4 + lr) ? Lq[TIX(4 + lr, k)] : 0.f;
                Ld[lr * 8 + k] = hi ? hif : lo;
            }
        #pragma unroll
        for (int i = 0; i < 8; ++i)
            #pragma unroll
            for (int lr = 0; lr < 4; ++lr) {
                float acc = Pnc[i * 4 + lr];
                #pragma unroll
                for (int k = 0; k < 8; ++k) {
                    if (k <= i && k <= 4 + lr)   // static bound (max-l case)
                        acc += Lq[TIX(i, k)] * Ld[lr * 8 + k];
                }
                Pnc[i * 4 + lr] = acc;
            }
    }

    // ======== unpack H full (broadcast) ========
    float Hm[32];
    #pragma unroll
    for (int j = 0; j < 8; ++j) {
        float4 v = arena[288 + q * 9 + j];
        const int r = j >> 1, c0 = 4 * (j & 1);
        Hm[r * 8 + c0 + 0] = v.x; Hm[r * 8 + c0 + 1] = v.y;
        Hm[r * 8 + c0 + 2] = v.z; Hm[r * 8 + c0 + 3] = v.w;
    }

    // ======== full ns via pair exchange ========
    float nsf[8];
    #pragma unroll
    for (int r = 0; r < 4; ++r) {
        float sh = __shfl_xor(ns_own[r], 32);
        nsf[r]     = hi ? sh : ns_own[r];
        nsf[4 + r] = hi ? ns_own[r] : sh;
    }

    // ======== residual + prediction out ========
    float res[4], pr[4];
    #pragma unroll
    for (int i = 0; i < 4; ++i) {
        float acc = 0.f;
        #pragma unroll
        for (int j = 0; j < 8; ++j) acc += Hm[i * 8 + j] * nsf[j];
        pr[i] = acc;
    }
    res[0] = z.x - pr[0]; res[1] = z.y - pr[1];
    res[2] = z.z - pr[2]; res[3] = z.w - pr[3];
    if (!hi)
        *(reinterpret_cast<float4*>(out_pred) + b) =
            make_float4(pr[0], pr[1], pr[2], pr[3]);

    // ======== HPc[a][lr] = sum_j H[a,j] Pn[j, 4p+lr] ========
    float HPc[16];
    #pragma unroll
    for (int a = 0; a < 4; ++a)
        #pragma unroll
        for (int lr = 0; lr < 4; ++lr) {
            float acc = 0.f;
            #pragma unroll
            for (int j = 0; j < 8; ++j) acc += Hm[a * 8 + j] * Pnc[j * 4 + lr];
            HPc[a * 4 + lr] = acc;
        }

    // ======== S = HP H^T (pair-partial + merge) ========
    float Sf[16];
    #pragma unroll
    for (int a = 0; a < 4; ++a)
        #pragma unroll
        for (int c = 0; c < 4; ++c) {
            float part = 0.f;
            #pragma unroll
            for (int kl = 0; kl < 4; ++kl) {
                float hv = hi ? Hm[c * 8 + 4 + kl] : Hm[c * 8 + kl];
                part += HPc[a * 4 + kl] * hv;
            }
            Sf[a * 4 + c] = part + __shfl_xor(part, 32);
        }
    // Hm stays live only for nothing below -> dead

    // ======== stage mn; S += R; invert ========
    {
        float2* a2 = reinterpret_cast<float2*>(arena);
        const float2* g = reinterpret_cast<const float2*>(mnin) + (size_t)bb * 5;
        #pragma unroll
        for (int i = 0; i < 3; ++i) {
            int f = i * 64 + t;
            if (f < 160) a2[f] = g[f];
        }
    }
    __syncthreads();
    float Si[16];
    {
        const float2* a2 = reinterpret_cast<const float2*>(arena);
        float Lr[10];
        #pragma unroll
        for (int rr = 0; rr < 5; ++rr) {
            float2 v = a2[q * 5 + rr];
            Lr[2 * rr] = v.x; Lr[2 * rr + 1] = v.y;
        }
        #pragma unroll
        for (int i = 0; i < 4; ++i)
            #pragma unroll
            for (int j = 0; j <= i; ++j) {
                float acc = 0.f;
                #pragma unroll
                for (int k = 0; k <= j; ++k)
                    acc += Lr[TIX(i, k)] * Lr[TIX(j, k)];
                Sf[i * 4 + j] += acc;
                if (i != j) Sf[j * 4 + i] += acc;
            }
        inv4(Sf, Si);
    }

    // ======== upd_state (own rows) ========
    float w[4];
    #pragma unroll
    for (int a = 0; a < 4; ++a) {
        float acc = 0.f;
        #pragma unroll
        for (int c = 0; c < 4; ++c) acc += Si[a * 4 + c] * res[c];
        w[a] = acc;
    }
    float us[4];
    #pragma unroll
    for (int r = 0; r < 4; ++r) {
        float acc = ns_own[r];
        #pragma unroll
        for (int a = 0; a < 4; ++a) acc += HPc[a * 4 + r] * w[a];
        us[r] = acc;
    }
    // state out: batch q slots {3q, 3q+1}, lane p writes its half
    arena[q * 3 + p] = make_float4(us[0], us[1], us[2], us[3]);
    __syncthreads();
    {
        float4* g = reinterpret_cast<float4*>(out_state) + (size_t)bb * 2;
        g[t] = arena[(t >> 1) * 3 + (t & 1)];
    }

    // ======== upd_cov = Pn - HP^T Si HP (own columns) ========
    float M[16];  // M[a][lr] = (Si HP)[a][4p+lr]
    #pragma unroll
    for (int a = 0; a < 4; ++a)
        #pragma unroll
        for (int lr = 0; lr < 4; ++lr) {
            float acc = 0.f;
            #pragma unroll
            for (int c = 0; c < 4; ++c) acc += Si[a * 4 + c] * HPc[c * 4 + lr];
            M[a * 4 + lr] = acc;
        }
    #pragma unroll
    for (int i = 0; i < 8; ++i) {
        const int r = i & 3;
        const bool own = ((i >> 2) == p);
        float hp[4];
        #pragma unroll
        for (int a = 0; a < 4; ++a) {
            float sh = __shfl_xor(HPc[a * 4 + r], 32);
            hp[a] = own ? HPc[a * 4 + r] : sh;
        }
        float cv[4];
        #pragma unroll
        for (int lr = 0; lr < 4; ++lr) {
            float acc = Pnc[i * 4 + lr];
            #pragma unroll
            for (int a = 0; a < 4; ++a) acc -= hp[a] * M[a * 4 + lr];
            cv[lr] = acc;
        }
        // row i, cols 4p..4p+3 = f4 slot s = i*2+p; swizzle ^ (q&7)
        arena[q * 16 + ((i * 2 + p) ^ (q & 7))] = make_float4(cv[0], cv[1], cv[2], cv[3]);
    }
    __syncthreads();
    {
        float4* g = reinterpret_cast<float4*>(out_cov) + (size_t)bb * 16;
        #pragma unroll
        for (int i = 0; i < 8; ++i) {
            int f = i * 64 + t;
            int qq = f >> 4, ss = f & 15;
            g[f] = arena[qq * 16 + (ss ^ (qq & 7))];
        }
    }
}

extern "C" void kernel_launch(void* const* d_in, const int* in_sizes, int n_in,
                              void* d_out, int out_size, void* d_ws, size_t ws_size,
                              hipStream_t stream) {
    const float* meas  = (const float*)d_in[0];
    const float* state = (const float*)d_in[1];
    const float* Pin   = (const float*)d_in[2];
    const float* Fin   = (const float*)d_in[3];
    const float* Hin   = (const float*)d_in[4];
    const float* pn    = (const float*)d_in[5];
    const float* mn    = (const float*)d_in[6];

    const int B = in_sizes[1] / 8;  // state is (B, 8); B = 262144 (divisible by 32)

    float* out = (float*)d_out;
    float* out_pred  = out;                       // B*4
    float* out_state = out + (size_t)B * 4;       // B*8
    float* out_cov   = out + (size_t)B * 12;      // B*64

    dim3 block(64);
    dim3 grid(B / 32);  // 32 batches per 1-wave block
    ekf_kernel<<<grid, block, 0, stream>>>(meas, state, Pin, Fin, Hin, pn, mn,
                                           out_pred, out_state, out_cov);
}

// Round 9
// 270.649 us; speedup vs baseline: 1.7647x; 1.7647x over previous
//
#include <hip/hip_runtime.h>

#define DEVINL __device__ __forceinline__
#define TIX(i, j) ((i) * ((i) + 1) / 2 + (j))

DEVINL void inv4(const float* m, float* inv) {
    float s0 = m[0] * m[5] - m[1] * m[4];
    float s1 = m[0] * m[6] - m[2] * m[4];
    float s2 = m[0] * m[7] - m[3] * m[4];
    float s3 = m[1] * m[6] - m[2] * m[5];
    float s4 = m[1] * m[7] - m[3] * m[5];
    float s5 = m[2] * m[7] - m[3] * m[6];
    float c5 = m[10] * m[15] - m[11] * m[14];
    float c4 = m[9] * m[15] - m[11] * m[13];
    float c3 = m[9] * m[14] - m[10] * m[13];
    float c2 = m[8] * m[15] - m[11] * m[12];
    float c1 = m[8] * m[14] - m[10] * m[12];
    float c0 = m[8] * m[13] - m[9] * m[12];
    float det = s0 * c5 - s1 * c4 + s2 * c3 + s3 * c2 - s4 * c1 + s5 * c0;
    float id = 1.0f / det;
    inv[0]  = ( m[5] * c5 - m[6] * c4 + m[7] * c3) * id;
    inv[1]  = (-m[1] * c5 + m[2] * c4 - m[3] * c3) * id;
    inv[2]  = ( m[13] * s5 - m[14] * s4 + m[15] * s3) * id;
    inv[3]  = (-m[9] * s5 + m[10] * s4 - m[11] * s3) * id;
    inv[4]  = (-m[4] * c5 + m[6] * c2 - m[7] * c1) * id;
    inv[5]  = ( m[0] * c5 - m[2] * c2 + m[3] * c1) * id;
    inv[6]  = (-m[12] * s5 + m[14] * s2 - m[15] * s1) * id;
    inv[7]  = ( m[8] * s5 - m[10] * s2 + m[11] * s1) * id;
    inv[8]  = ( m[4] * c4 - m[5] * c2 + m[7] * c0) * id;
    inv[9]  = (-m[0] * c4 + m[1] * c2 - m[3] * c0) * id;
    inv[10] = ( m[12] * s4 - m[13] * s2 + m[15] * s0) * id;
    inv[11] = (-m[8] * s4 + m[9] * s2 - m[11] * s0) * id;
    inv[12] = (-m[4] * c3 + m[5] * c1 - m[6] * c0) * id;
    inv[13] = ( m[0] * c3 - m[1] * c1 + m[2] * c0) * id;
    inv[14] = (-m[12] * s3 + m[13] * s1 - m[14] * s0) * id;
    inv[15] = ( m[8] * s3 - m[9] * s1 + m[10] * s0) * id;
}

// EIGHT LANES PER BATCH: lane group (8 lanes) owns one batch; lane r owns
// row r of every 8-dim object (F row, P row, Lq row, Pn row, cov row) and
// column r of H (4 floats). No object is ever held in full by one lane ->
// per-lane registers ~60-80 by construction (R8 lesson: duplicated state
// defeats lane-splitting). No LDS, NO barriers at all; all cross-lane data
// moves via __shfl(.,j,8) broadcasts / __shfl_xor butterflies (LDS pipe,
// concurrent with VALU). Loads/stores perfectly coalesced without staging:
// lane r reads F[b][8r..8r+7] -> wave covers 2KB contiguous.
// Rationale: R1-R8 show dur ~= hbm_bytes/achieved_BW with achieved BW rising
// with resident waves (R8: 42% occ -> 3.46 TB/s). Smaller VGPR bin + short
// chains = more waves = more outstanding loads = BW.
__global__ __launch_bounds__(256) void ekf_kernel(
    const float* __restrict__ meas,   // (B,4)
    const float* __restrict__ state,  // (B,8)
    const float* __restrict__ Pin,    // (B,8,8) symmetric
    const float* __restrict__ Fin,    // (B,8,8)
    const float* __restrict__ Hin,    // (B,4,8)
    const float* __restrict__ pnin,   // (B,36)
    const float* __restrict__ mnin,   // (B,10)
    float* __restrict__ out_pred,     // (B,4)
    float* __restrict__ out_state,    // (B,8)
    float* __restrict__ out_cov)      // (B,8,8)
{
    const int gt = blockIdx.x * 256 + threadIdx.x;
    const int b  = gt >> 3;           // batch
    const int r  = gt & 7;            // owned row

    // ---------------- direct loads (wave-contiguous) ----------------
    float fr[8], pr[8];
    {
        const float4* gf = reinterpret_cast<const float4*>(Fin + (size_t)b * 64 + r * 8);
        float4 a = gf[0], c = gf[1];
        fr[0]=a.x; fr[1]=a.y; fr[2]=a.z; fr[3]=a.w;
        fr[4]=c.x; fr[5]=c.y; fr[6]=c.z; fr[7]=c.w;
        const float4* gp = reinterpret_cast<const float4*>(Pin + (size_t)b * 64 + r * 8);
        float4 d = gp[0], e = gp[1];
        pr[0]=d.x; pr[1]=d.y; pr[2]=d.z; pr[3]=d.w;
        pr[4]=e.x; pr[5]=e.y; pr[6]=e.z; pr[7]=e.w;
    }
    // Lq row r: contiguous at TIX(r,0), length r+1; over-read stays inside
    // the batch's 36-float block (TIX(r,0)+7 <= 35 for all r), mask k>r to 0.
    float lq[8];
    {
        const float* lp = pnin + (size_t)b * 36 + ((r * (r + 1)) >> 1);
        #pragma unroll
        for (int k = 0; k < 8; ++k) { float v = lp[k]; lq[k] = (k <= r) ? v : 0.f; }
    }
    float hc[4];   // H column r
    #pragma unroll
    for (int a = 0; a < 4; ++a) hc[a] = Hin[(size_t)b * 32 + a * 8 + r];
    float sc = state[(size_t)b * 8 + r];
    float4 z = *reinterpret_cast<const float4*>(meas + (size_t)b * 4);

    // ---------------- ns[r] = F row r . s ----------------
    float ns = 0.f;
    #pragma unroll
    for (int j = 0; j < 8; ++j) ns += fr[j] * __shfl(sc, j, 8);

    // ---------------- G[r][l] = P row r . F row l ----------------
    float g[8];
    #pragma unroll
    for (int l = 0; l < 8; ++l) {
        float acc = 0.f;
        #pragma unroll
        for (int k = 0; k < 8; ++k) acc += pr[k] * __shfl(fr[k], l, 8);
        g[l] = acc;
    }

    // ---------------- Pn[r][l] = sum_j F[r,j] G[j][l] ----------------
    float pn_[8] = {0, 0, 0, 0, 0, 0, 0, 0};
    #pragma unroll
    for (int j = 0; j < 8; ++j) {
        const float frj = fr[j];
        #pragma unroll
        for (int l = 0; l < 8; ++l) pn_[l] += frj * __shfl(g[l], j, 8);
    }

    // ---------------- Pn += Q, Q[r][l] = sum_{k<=l} lq[k]*Lq[l][k] ----------------
    // (lq[k]=0 for k>r covers the k<=min(r,l) bound)
    #pragma unroll
    for (int l = 0; l < 8; ++l) {
        float acc = 0.f;
        #pragma unroll
        for (int k = 0; k <= l; ++k) acc += lq[k] * __shfl(lq[k], l, 8);
        pn_[l] += acc;
    }

    // ---------------- prediction (butterfly over the 8-group) ----------------
    float pd[4];
    #pragma unroll
    for (int a = 0; a < 4; ++a) pd[a] = hc[a] * ns;
    #pragma unroll
    for (int a = 0; a < 4; ++a) {
        pd[a] += __shfl_xor(pd[a], 1, 8);
        pd[a] += __shfl_xor(pd[a], 2, 8);
        pd[a] += __shfl_xor(pd[a], 4, 8);
    }
    float res[4] = { z.x - pd[0], z.y - pd[1], z.z - pd[2], z.w - pd[3] };
    if (r < 4) {
        float pv = pd[0];
        pv = (r == 1) ? pd[1] : pv;
        pv = (r == 2) ? pd[2] : pv;
        pv = (r == 3) ? pd[3] : pv;
        out_pred[(size_t)b * 4 + r] = pv;
    }

    // ---------------- hp[a] = HP[a][r] = sum_j Pn[r,j] H[a,j] (Pn sym) ----------------
    float hp[4] = {0, 0, 0, 0};
    #pragma unroll
    for (int j = 0; j < 8; ++j) {
        const float pj = pn_[j];
        #pragma unroll
        for (int a = 0; a < 4; ++a) hp[a] += pj * __shfl(hc[a], j, 8);
    }

    // ---------------- S = HP H^T (+R) via per-lane outer + butterfly ----------------
    float S[16];
    #pragma unroll
    for (int a = 0; a < 4; ++a)
        #pragma unroll
        for (int c = 0; c < 4; ++c) S[a * 4 + c] = hp[a] * hc[c];
    #pragma unroll
    for (int e = 0; e < 16; ++e) {
        S[e] += __shfl_xor(S[e], 1, 8);
        S[e] += __shfl_xor(S[e], 2, 8);
        S[e] += __shfl_xor(S[e], 4, 8);
    }
    {   // R = Lr Lr^T, each lane redundantly (small)
        float lr[10];
        const float2* g2 = reinterpret_cast<const float2*>(mnin + (size_t)b * 10);
        #pragma unroll
        for (int i = 0; i < 5; ++i) { float2 v = g2[i]; lr[2 * i] = v.x; lr[2 * i + 1] = v.y; }
        #pragma unroll
        for (int a = 0; a < 4; ++a)
            #pragma unroll
            for (int c = 0; c <= a; ++c) {
                float acc = 0.f;
                #pragma unroll
                for (int k = 0; k <= c; ++k) acc += lr[TIX(a, k)] * lr[TIX(c, k)];
                S[a * 4 + c] += acc;
                if (a != c) S[c * 4 + a] += acc;
            }
    }
    float Si[16];
    inv4(S, Si);

    // ---------------- upd_state[r] = ns + sum_a hp[a] w[a] ----------------
    float w[4];
    #pragma unroll
    for (int a = 0; a < 4; ++a) {
        float acc = 0.f;
        #pragma unroll
        for (int c = 0; c < 4; ++c) acc += Si[a * 4 + c] * res[c];
        w[a] = acc;
    }
    float us = ns;
    #pragma unroll
    for (int a = 0; a < 4; ++a) us += hp[a] * w[a];
    out_state[(size_t)b * 8 + r] = us;

    // ---------------- m[a] = (Si HP)[a][r] ----------------
    float m_[4];
    #pragma unroll
    for (int a = 0; a < 4; ++a) {
        float acc = 0.f;
        #pragma unroll
        for (int c = 0; c < 4; ++c) acc += Si[a * 4 + c] * hp[c];
        m_[a] = acc;
    }

    // ---------------- cov[r][l] = Pn[r,l] - sum_a HP[a,r] M[a,l] ----------------
    float cv[8];
    #pragma unroll
    for (int l = 0; l < 8; ++l) {
        float acc = pn_[l];
        #pragma unroll
        for (int a = 0; a < 4; ++a) acc -= hp[a] * __shfl(m_[a], l, 8);
        cv[l] = acc;
    }
    float4* oc = reinterpret_cast<float4*>(out_cov + (size_t)b * 64 + r * 8);
    oc[0] = make_float4(cv[0], cv[1], cv[2], cv[3]);
    oc[1] = make_float4(cv[4], cv[5], cv[6], cv[7]);
}

extern "C" void kernel_launch(void* const* d_in, const int* in_sizes, int n_in,
                              void* d_out, int out_size, void* d_ws, size_t ws_size,
                              hipStream_t stream) {
    const float* meas  = (const float*)d_in[0];
    const float* state = (const float*)d_in[1];
    const float* Pin   = (const float*)d_in[2];
    const float* Fin   = (const float*)d_in[3];
    const float* Hin   = (const float*)d_in[4];
    const float* pn    = (const float*)d_in[5];
    const float* mn    = (const float*)d_in[6];

    const int B = in_sizes[1] / 8;  // state is (B, 8); B = 262144

    float* out = (float*)d_out;
    float* out_pred  = out;                       // B*4
    float* out_state = out + (size_t)B * 4;       // B*8
    float* out_cov   = out + (size_t)B * 12;      // B*64

    dim3 block(256);
    dim3 grid((B * 8) / 256);   // 8 lanes per batch, 32 batches per block
    ekf_kernel<<<grid, block, 0, stream>>>(meas, state, Pin, Fin, Hin, pn, mn,
                                           out_pred, out_state, out_cov);
}